// Round 6
// baseline (202.126 us; speedup 1.0000x reference)
//
#include <hip/hip_runtime.h>

typedef _Float16 f16;
typedef _Float16 f16x2 __attribute__((ext_vector_type(2)));
typedef _Float16 f16x8 __attribute__((ext_vector_type(8)));
typedef float f32x4 __attribute__((ext_vector_type(4)));

#define INV_R (1.0f / 40.0f)
#define NBLK 256

// ---- workspace layout (bytes), ~3.05 MB ----
#define OFF_HTA  0u          // f16 [80][512]  hT buffer A (prep: feats0^T)
#define OFF_HTB  81920u      // f16 [80][512]  hT buffer B
#define OFF_KT0  163840u     // f16 544*64*8   layer-0 packed kernel (conv|dense|pad)
#define OFF_KT1  720896u     // f16 520*64*8
#define OFF_KT2  1253376u
#define OFF_KT3  1785856u
#define OFF_KT4  2318336u
#define OFF_HG   2850816u    // f16 [512][64]  h by m-row (dense-tail source, self-read)
#define OFF_OG   2916352u    // f32 [512][64]  out by m-row (residual, self-read)
#define OFF_BAR  3047424u    // u32 [576] hierarchical barrier (memset 0 per call)

#define PREP_TOTAL 1384448

// ============ hierarchical grid barrier (proven r5, NBLK=256) ============
__device__ __forceinline__ unsigned bar_ld(unsigned* p) {
  return __hip_atomic_load(p, __ATOMIC_RELAXED, __HIP_MEMORY_SCOPE_AGENT);
}
__device__ void gridbar(unsigned* bar, int phase) {
  __syncthreads();
  if (threadIdx.x == 0) {
    int bid = blockIdx.x;
    int xcd = bid & 7;
    unsigned* xcnt = bar + xcd * 32 + phase;
    unsigned* xrel = bar + 256 + xcd * 32 + phase;
    unsigned* gcnt = bar + 512 + phase;
    unsigned* grel = bar + 544 + phase;
    __threadfence();                   // release: flush my block's writes
    __hip_atomic_fetch_add(xcnt, 1u, __ATOMIC_RELAXED, __HIP_MEMORY_SCOPE_AGENT);
    if (bid < 8) {
      while (bar_ld(xcnt) < (NBLK / 8)) __builtin_amdgcn_s_sleep(2);
      __hip_atomic_fetch_add(gcnt, 1u, __ATOMIC_RELAXED, __HIP_MEMORY_SCOPE_AGENT);
      if (bid == 0) {
        while (bar_ld(gcnt) < 8u) __builtin_amdgcn_s_sleep(2);
        __hip_atomic_store(grel, 1u, __ATOMIC_RELAXED, __HIP_MEMORY_SCOPE_AGENT);
      } else {
        while (bar_ld(grel) == 0u) __builtin_amdgcn_s_sleep(2);
      }
      __hip_atomic_store(xrel, 1u, __ATOMIC_RELAXED, __HIP_MEMORY_SCOPE_AGENT);
    } else {
      while (bar_ld(xrel) == 0u) __builtin_amdgcn_s_sleep(4);
    }
    __threadfence();                   // acquire: invalidate stale cached lines
  }
  __syncthreads();
}

// ================= math helpers =================
__device__ __forceinline__ float feats0_val(int ch, int n, const float* v, const float* other) {
  if (ch == 0) return 1.0f;
  if (ch < 4) return v[n * 3 + (ch - 1)];
  return other[n * 62 + (ch - 4)];
}
__device__ __forceinline__ float atan_poly(float t) {
  float t2 = t * t;
  float p = -0.0117212f;
  p = p * t2 + 0.05265332f;
  p = p * t2 - 0.11643287f;
  p = p * t2 + 0.19354346f;
  p = p * t2 - 0.33262347f;
  p = p * t2 + 0.99997726f;
  return t * p;
}
__device__ __forceinline__ void axis_w(float g, int& i0c, int& i1c, float& w0, float& w1) {
  float c = 2.0f * g + 1.5f;
  float fl = floorf(c);
  float f = c - fl;
  int i0 = (int)fl;
  w0 = (i0 >= 0 && i0 <= 3) ? (1.0f - f) : 0.0f;
  w1 = (i0 >= -1 && i0 <= 2) ? f : 0.0f;
  i0c = min(max(i0, 0), 3);
  i1c = min(max(i0 + 1, 0), 3);
}
__device__ __forceinline__ float dot2f(f16x2 a, f16x2 b, float c) {
#if defined(__has_builtin) && __has_builtin(__builtin_amdgcn_fdot2)
  return __builtin_amdgcn_fdot2(a, b, c, false);
#else
  return c + (float)a[0] * (float)b[0] + (float)a[1] * (float)b[1];
#endif
}

// ============ prep: hT0 + packed KT4 for all 5 layers ============
// KT layout per layer: elem ((g8*64 + o)*8 + e) = K_row_o[g8*8 + e], f16.
// Lane o reads 16B at ((g8*64+o)*8)*2 -> 64 lanes = 1KB contiguous (coalesced).
__device__ void prep_body(const float* __restrict__ v, const float* __restrict__ other,
                          const float* __restrict__ kf, const float* __restrict__ Wf,
                          const float* __restrict__ k1, const float* __restrict__ W1,
                          const float* __restrict__ k2, const float* __restrict__ W2,
                          const float* __restrict__ k3, const float* __restrict__ W3,
                          const float* __restrict__ k4, const float* __restrict__ W4,
                          char* __restrict__ ws) {
  f16* hTA = (f16*)(ws + OFF_HTA);
  for (int idx = blockIdx.x * 256 + threadIdx.x; idx < PREP_TOTAL; idx += NBLK * 256) {
    int e = idx;
    if (e < 40960) {                         // hT0: feats0^T, rows 66..79 zero
      int i = e >> 9, n = e & 511;
      hTA[e] = (f16)((i < 66) ? feats0_val(i, n, v, other) : 0.0f);
      continue;
    }
    e -= 40960;
    if (e < 278528) {                        // KT0: conv 4224 | dense 66 | pad->4352
      int o = (e >> 3) & 63;
      int k = ((e >> 9) << 3) + (e & 7);
      float val = 0.0f;
      if (k < 4224) { if (o < 32) val = kf[o * 4224 + k]; }
      else if (k < 4290) { if (o >= 32) val = Wf[(o - 32) * 66 + (k - 4224)]; }
      ((f16*)(ws + OFF_KT0))[e] = (f16)val;
      continue;
    }
    e -= 278528;
    if (e < 798720) {                        // KT1..KT3: conv 4096 | dense 64
      int which = e / 266240, ee = e % 266240;
      const float* kk = which == 0 ? k1 : (which == 1 ? k2 : k3);
      const float* WW = which == 0 ? W1 : (which == 1 ? W2 : W3);
      int o = (ee >> 3) & 63;
      int k = ((ee >> 9) << 3) + (ee & 7);
      float val = (k < 4096) ? kk[o * 4096 + k] : WW[o * 64 + (k - 4096)];
      ((f16*)(ws + OFF_KT1))[(size_t)which * 266240 + ee] = (f16)val;
      continue;
    }
    e -= 798720;
    {                                        // KT4: rows o<6 real, else zero
      int o = (e >> 3) & 63;
      int k = ((e >> 9) << 3) + (e & 7);
      float val = 0.0f;
      if (o < 6) val = (k < 4096) ? k4[o * 4096 + k] : W4[o * 64 + (k - 4096)];
      ((f16*)(ws + OFF_KT4))[e] = (f16)val;
    }
  }
}

// ============ fused layer: stage1 (W-scatter + MFMA -> t in LDS) + stage2 (dot) ============
// Block b owns m0=b, m1=b+256. t never leaves LDS. Only hT (64KB grid-wide) crosses blocks.
template<int LAYER>
__device__ void layer_body(const float* __restrict__ p, const float* __restrict__ mask,
                           const float* __restrict__ v, const float* __restrict__ other,
                           const float* __restrict__ bias, const f16* __restrict__ KT,
                           const f16* __restrict__ hT_in, f16* __restrict__ hT_out,
                           f16* __restrict__ hG, float* __restrict__ outG,
                           float* __restrict__ dout,
                           f16* __restrict__ Wl, f16* __restrict__ tt, float* __restrict__ red) {
  constexpr int CI     = (LAYER == 0) ? 66 : 64;
  constexpr int ITILES = (LAYER == 0) ? 5 : 4;
  constexpr int KD     = (LAYER == 0) ? 4352 : 4160;
  constexpr bool RES   = (LAYER >= 1 && LAYER <= 3);
  constexpr bool FINAL = (LAYER == 4);
  const int tid = threadIdx.x;
  const int b = blockIdx.x;
  const int wave = tid >> 6, lane = tid & 63;
  const int row = lane & 15, kgrp = lane >> 4;
  const int grow = wave * 16 + row;

  // ---------- stage 1: per m, two n-halves (W is [64g][256n], 32KB) ----------
  #pragma unroll
  for (int mi = 0; mi < 2; ++mi) {
    const int m = b + mi * NBLK;
    const float pmx = p[m * 3 + 0], pmy = p[m * 3 + 1], pmz = p[m * 3 + 2];
    f32x4 acc[ITILES];
    #pragma unroll
    for (int it = 0; it < ITILES; ++it) acc[it] = f32x4{0.f, 0.f, 0.f, 0.f};

    #pragma unroll
    for (int half = 0; half < 2; ++half) {
      __syncthreads();                       // previous MFMA readers done with W
      int4* w4 = (int4*)Wl;
      int4 z4 = make_int4(0, 0, 0, 0);
      #pragma unroll
      for (int i = 0; i < 8; ++i) w4[tid + i * 256] = z4;   // zero 32KB
      __syncthreads();
      {
        const int n = half * 256 + tid;
        float x = (p[n * 3 + 0] - pmx) * INV_R;
        float y = (p[n * 3 + 1] - pmy) * INV_R;
        float z = (p[n * 3 + 2] - pmz) * INV_R;
        float r2 = x * x + y * y + z * z;
        float q = 1.0f - r2;
        float att = (q > 0.0f) ? q * q * q * mask[n] : 0.0f;
        bool c1 = (x == 0.0f) && (y == 0.0f);
        bool c2 = (fabsf(y) <= fabsf(x)) && !c1;
        float r = sqrtf(x * x + y * y + 1e-9f);
        float num = c2 ? y : x;
        float den = c2 ? x : y;
        float a = atan_poly(num / den);
        float s2 = copysignf(r, x), s3 = copysignf(r, y);
        const float C4PI = 1.2732395447351628f;
        float xs = c1 ? 0.0f : (c2 ? s2 : C4PI * s3 * a);
        float ys = c1 ? 0.0f : (c2 ? C4PI * s2 * a : s3);
        float zs = z;
        int iz0, iz1, iy0, iy1, ix0, ix1;
        float wz0, wz1, wy0, wy1, wx0, wx1;
        axis_w(zs, iz0, iz1, wz0, wz1);
        axis_w(ys, iy0, iy1, wy0, wy1);
        axis_w(xs, ix0, ix1, wx0, wx1);
        wz0 *= att; wz1 *= att;
        int gz[2] = {iz0 * 16, iz1 * 16};
        int gy[2] = {iy0 * 4, iy1 * 4};
        int gx[2] = {ix0, ix1};
        float wzv[2] = {wz0, wz1}, wyv[2] = {wy0, wy1}, wxv[2] = {wx0, wx1};
        #pragma unroll
        for (int za = 0; za < 2; ++za)
          #pragma unroll
          for (int ya = 0; ya < 2; ++ya)
            #pragma unroll
            for (int xa = 0; xa < 2; ++xa) {
              float w = wzv[za] * wyv[ya] * wxv[xa];
              if (w != 0.0f) {
                int g = gz[za] + gy[ya] + gx[xa];
                Wl[g * 256 + (tid ^ ((g & 7) << 3))] = (f16)w;
              }
            }
      }
      __syncthreads();
      #pragma unroll
      for (int k0 = 0; k0 < 8; ++k0) {
        const int n0l = k0 * 32 + kgrp * 8;
        f16x8 afrag = *(f16x8*)&Wl[grow * 256 + (n0l ^ ((grow & 7) << 3))];
        #pragma unroll
        for (int it = 0; it < ITILES; ++it) {
          f16x8 bfrag = *(const f16x8*)&hT_in[(it * 16 + row) * 512 + half * 256 + n0l];
          acc[it] = __builtin_amdgcn_mfma_f32_16x16x32_f16(afrag, bfrag, acc[it], 0, 0, 0);
        }
      }
    }
    // write t[mi] = [i*64+g], plus dense tail
    const int g4 = wave * 16 + kgrp * 4;
    #pragma unroll
    for (int it = 0; it < ITILES; ++it) {
      const int icol = it * 16 + row;
      if (icol < CI) {
        union { f16 h[4]; short4 s; } cv;
        #pragma unroll
        for (int r = 0; r < 4; ++r) cv.h[r] = (f16)acc[it][r];
        *(short4*)&tt[mi * 4352 + icol * 64 + g4] = cv.s;
      }
    }
    if (LAYER == 0) {
      if (tid < 128)
        tt[mi * 4352 + 4224 + tid] = (f16)((tid < 66) ? feats0_val(tid, m, v, other) : 0.0f);
    } else {
      if (tid < 64) tt[mi * 4352 + 4096 + tid] = hG[m * 64 + tid];   // self-written row
    }
  }
  __syncthreads();

  // ---------- stage 2: out[m,o] = t[m,:] . K[o,:] via dot2, wave = k-split ----------
  constexpr int GPS = KD / 32;               // k8-groups per wave
  {
    const int o = tid & 63, wv = tid >> 6;
    float a0 = 0.f, a1 = 0.f;
    const f16* kp  = KT + ((size_t)(wv * GPS) * 64 + o) * 8;
    const f16* t0p = tt + (size_t)(wv * GPS) * 8;
    const f16* t1p = tt + 4352 + (size_t)(wv * GPS) * 8;
    for (int g = 0; g < GPS; ++g) {
      union { f16x8 v8; f16x2 p2[4]; } uk, u0, u1;
      uk.v8 = *(const f16x8*)kp;
      u0.v8 = *(const f16x8*)t0p;             // LDS broadcast (same addr per wave)
      u1.v8 = *(const f16x8*)t1p;
      kp += 512; t0p += 8; t1p += 8;
      #pragma unroll
      for (int j = 0; j < 4; ++j) {
        a0 = dot2f(uk.p2[j], u0.p2[j], a0);
        a1 = dot2f(uk.p2[j], u1.p2[j], a1);
      }
    }
    red[wv * 128 + o]      = a0;
    red[wv * 128 + 64 + o] = a1;
  }
  __syncthreads();
  if (tid < 128) {
    const int mi = tid >> 6, oo = tid & 63;
    const int m = b + mi * NBLK;
    float s = red[mi * 64 + oo] + red[128 + mi * 64 + oo]
            + red[256 + mi * 64 + oo] + red[384 + mi * 64 + oo];
    if (FINAL) {
      if (oo < 6) dout[m * 6 + oo] = s + bias[oo];
    } else {
      float bb = (LAYER == 0) ? ((oo < 32) ? 0.0f : bias[oo - 32]) : bias[oo];
      float val = s + bb;
      if (RES) val += outG[m * 64 + oo];      // self-written row
      outG[m * 64 + oo] = val;
      float h = fmaxf(val, 0.0f);
      hG[m * 64 + oo] = (f16)h;
      hT_out[oo * 512 + m] = (f16)h;          // cross-block: next layer's B operand
    }
  }
}

// ================= cooperative mega-kernel =================
__global__ __launch_bounds__(256) void mega_kernel(
    const float* p, const float* v, const float* other, const float* mask,
    const float* kf, const float* Wf, const float* bf,
    const float* k1, const float* W1, const float* b1,
    const float* k2, const float* W2, const float* b2,
    const float* k3, const float* W3, const float* b3,
    const float* k4, const float* W4, const float* b4,
    float* dout, char* ws) {
  __shared__ int4 blob[3264];                // 52224 B: W 32KB | t 17KB | red 2KB
  f16* Wl = (f16*)blob;
  f16* tt = Wl + 16384;
  float* red = (float*)(tt + 8704);
  unsigned* bar = (unsigned*)(ws + OFF_BAR);

  f16* hTA = (f16*)(ws + OFF_HTA);
  f16* hTB = (f16*)(ws + OFF_HTB);
  f16* hG  = (f16*)(ws + OFF_HG);
  float* outG = (float*)(ws + OFF_OG);

  prep_body(v, other, kf, Wf, k1, W1, k2, W2, k3, W3, k4, W4, ws);
  gridbar(bar, 0);
  layer_body<0>(p, mask, v, other, bf, (const f16*)(ws + OFF_KT0), hTA, hTB, hG, outG, nullptr, Wl, tt, red);
  gridbar(bar, 1);
  layer_body<1>(p, mask, v, other, b1, (const f16*)(ws + OFF_KT1), hTB, hTA, hG, outG, nullptr, Wl, tt, red);
  gridbar(bar, 2);
  layer_body<2>(p, mask, v, other, b2, (const f16*)(ws + OFF_KT2), hTA, hTB, hG, outG, nullptr, Wl, tt, red);
  gridbar(bar, 3);
  layer_body<3>(p, mask, v, other, b3, (const f16*)(ws + OFF_KT3), hTB, hTA, hG, outG, nullptr, Wl, tt, red);
  gridbar(bar, 4);
  layer_body<4>(p, mask, v, other, b4, (const f16*)(ws + OFF_KT4), hTA, nullptr, hG, outG, dout, Wl, tt, red);
}

// ================= fallback: 6 plain launches of the same bodies =================
__global__ __launch_bounds__(256) void prep_g(
    const float* v, const float* other, const float* kf, const float* Wf,
    const float* k1, const float* W1, const float* k2, const float* W2,
    const float* k3, const float* W3, const float* k4, const float* W4, char* ws) {
  prep_body(v, other, kf, Wf, k1, W1, k2, W2, k3, W3, k4, W4, ws);
}

template<int LAYER>
__global__ __launch_bounds__(256) void layer_g(
    const float* p, const float* mask, const float* v, const float* other,
    const float* bias, const f16* KT, const f16* hT_in, f16* hT_out,
    f16* hG, float* outG, float* dout) {
  __shared__ int4 blob[3264];
  f16* Wl = (f16*)blob;
  f16* tt = Wl + 16384;
  float* red = (float*)(tt + 8704);
  layer_body<LAYER>(p, mask, v, other, bias, KT, hT_in, hT_out, hG, outG, dout, Wl, tt, red);
}

extern "C" void kernel_launch(void* const* d_in, const int* in_sizes, int n_in,
                              void* d_out, int out_size, void* d_ws, size_t ws_size,
                              hipStream_t stream) {
  const float* p     = (const float*)d_in[0];
  const float* v     = (const float*)d_in[1];
  const float* other = (const float*)d_in[2];
  const float* mask  = (const float*)d_in[3];
  const float* kf    = (const float*)d_in[4];
  const float* Wf    = (const float*)d_in[5];
  const float* bf    = (const float*)d_in[6];
  const float* k1    = (const float*)d_in[7];
  const float* W1    = (const float*)d_in[8];
  const float* b1    = (const float*)d_in[9];
  const float* k2    = (const float*)d_in[10];
  const float* W2    = (const float*)d_in[11];
  const float* b2    = (const float*)d_in[12];
  const float* k3    = (const float*)d_in[13];
  const float* W3    = (const float*)d_in[14];
  const float* b3    = (const float*)d_in[15];
  const float* k4    = (const float*)d_in[16];
  const float* W4    = (const float*)d_in[17];
  const float* b4    = (const float*)d_in[18];
  float* dout = (float*)d_out;
  char* ws = (char*)d_ws;
  (void)in_sizes; (void)n_in; (void)out_size; (void)ws_size;

  const f16* KT0 = (const f16*)(ws + OFF_KT0);
  const f16* KT1 = (const f16*)(ws + OFF_KT1);
  const f16* KT2 = (const f16*)(ws + OFF_KT2);
  const f16* KT3 = (const f16*)(ws + OFF_KT3);
  const f16* KT4c = (const f16*)(ws + OFF_KT4);
  f16* hTA = (f16*)(ws + OFF_HTA);
  f16* hTB = (f16*)(ws + OFF_HTB);
  f16* hG  = (f16*)(ws + OFF_HG);
  float* outG = (float*)(ws + OFF_OG);

  // ---- cooperative fused path ----
  int maxb = 0;
  hipError_t e1 = hipOccupancyMaxActiveBlocksPerMultiprocessor(
      &maxb, (const void*)mega_kernel, 256, 0);
  if (e1 == hipSuccess && maxb >= 1) {
    hipMemsetAsync(ws + OFF_BAR, 0, 2304, stream);
    void* args[] = {
      (void*)&p, (void*)&v, (void*)&other, (void*)&mask,
      (void*)&kf, (void*)&Wf, (void*)&bf,
      (void*)&k1, (void*)&W1, (void*)&b1,
      (void*)&k2, (void*)&W2, (void*)&b2,
      (void*)&k3, (void*)&W3, (void*)&b3,
      (void*)&k4, (void*)&W4, (void*)&b4,
      (void*)&dout, (void*)&ws
    };
    hipError_t e2 = hipLaunchCooperativeKernel((const void*)mega_kernel, dim3(NBLK),
                                               dim3(256), args, 0, stream);
    if (e2 == hipSuccess) return;
  }

  // ---- fallback: same bodies, dispatch-boundary coherence ----
  prep_g<<<NBLK, 256, 0, stream>>>(v, other, kf, Wf, k1, W1, k2, W2, k3, W3, k4, W4, ws);
  layer_g<0><<<NBLK, 256, 0, stream>>>(p, mask, v, other, bf, KT0, hTA, hTB, hG, outG, nullptr);
  layer_g<1><<<NBLK, 256, 0, stream>>>(p, mask, v, other, b1, KT1, hTB, hTA, hG, outG, nullptr);
  layer_g<2><<<NBLK, 256, 0, stream>>>(p, mask, v, other, b2, KT2, hTA, hTB, hG, outG, nullptr);
  layer_g<3><<<NBLK, 256, 0, stream>>>(p, mask, v, other, b3, KT3, hTB, hTA, hG, outG, nullptr);
  layer_g<4><<<NBLK, 256, 0, stream>>>(p, mask, v, other, b4, KT4c, hTA, nullptr, hG, outG, dout);
}

// Round 7
// 185.446 us; speedup vs baseline: 1.0899x; 1.0899x over previous
//
#include <hip/hip_runtime.h>

typedef _Float16 f16;
typedef _Float16 f16x2 __attribute__((ext_vector_type(2)));
typedef _Float16 f16x8 __attribute__((ext_vector_type(8)));
typedef float f32x4 __attribute__((ext_vector_type(4)));

#define INV_R (1.0f / 40.0f)
#define NBLK 512

// ---- workspace layout (bytes), ~3.3 MB ----
// hT0..hT4: written once (sc01), read once next phase -> no stale-line hazard.
#define OFF_HT0  0u          // f16 [80][512]
#define OFF_HT1  81920u      // f16 [64][512] (80-row stride kept for uniformity)
#define OFF_HT2  163840u
#define OFF_HT3  245760u
#define OFF_HT4  327680u
#define OFF_KT0  409600u     // f16 544*64*8  packed layer-0 kernel (conv|dense|pad)
#define OFF_KT1  966656u     // f16 520*64*8
#define OFF_KT2  1499136u
#define OFF_KT3  2031616u
#define OFF_KT4  2564096u
#define OFF_HG   3096576u    // f16 [512][64]  h row (block-private: self-write/self-read)
#define OFF_OG   3162112u    // f32 [512][64]  out row (block-private residual)
#define OFF_BAR  3293184u    // u32 [576] hierarchical barrier (memset 0 per call)

#define PREP_TOTAL 1384448

// ---- system-scope (sc0 sc1) stores: write-through to coherent point, no L1/L2 allocate ----
__device__ __forceinline__ void st_sys_u16(void* p, unsigned v) {
  asm volatile("global_store_short %0, %1, off sc0 sc1" :: "v"(p), "v"(v) : "memory");
}
__device__ __forceinline__ unsigned f16bits(float x) {
  union { f16 h; unsigned short s; } cv; cv.h = (f16)x; return (unsigned)cv.s;
}

// ============ fence-free hierarchical grid barrier ============
// Correctness: all cross-block data was STORED with sc0/sc1 (coherent point);
// vmcnt(0) drains those stores before arrival. Readers' first touch of each
// cross-block line is post-barrier -> plain cached loads are safe. No fences.
__device__ __forceinline__ unsigned bar_ld(unsigned* p) {
  return __hip_atomic_load(p, __ATOMIC_RELAXED, __HIP_MEMORY_SCOPE_AGENT);
}
__device__ void gridbar(unsigned* bar, int phase) {
  asm volatile("s_waitcnt vmcnt(0)" ::: "memory");   // sc01 stores globally visible
  __syncthreads();
  if (threadIdx.x == 0) {
    int bid = blockIdx.x;
    int xcd = bid & 7;
    unsigned* xcnt = bar + xcd * 32 + phase;
    unsigned* xrel = bar + 256 + xcd * 32 + phase;
    unsigned* gcnt = bar + 512 + phase;
    unsigned* grel = bar + 544 + phase;
    __hip_atomic_fetch_add(xcnt, 1u, __ATOMIC_RELAXED, __HIP_MEMORY_SCOPE_AGENT);
    if (bid < 8) {
      while (bar_ld(xcnt) < (NBLK / 8)) __builtin_amdgcn_s_sleep(2);
      __hip_atomic_fetch_add(gcnt, 1u, __ATOMIC_RELAXED, __HIP_MEMORY_SCOPE_AGENT);
      if (bid == 0) {
        while (bar_ld(gcnt) < 8u) __builtin_amdgcn_s_sleep(2);
        __hip_atomic_store(grel, 1u, __ATOMIC_RELAXED, __HIP_MEMORY_SCOPE_AGENT);
      } else {
        while (bar_ld(grel) == 0u) __builtin_amdgcn_s_sleep(2);
      }
      __hip_atomic_store(xrel, 1u, __ATOMIC_RELAXED, __HIP_MEMORY_SCOPE_AGENT);
    } else {
      while (bar_ld(xrel) == 0u) __builtin_amdgcn_s_sleep(4);
    }
    asm volatile("" ::: "memory");
  }
  __syncthreads();
}

// ================= math helpers =================
__device__ __forceinline__ float feats0_val(int ch, int n, const float* v, const float* other) {
  if (ch == 0) return 1.0f;
  if (ch < 4) return v[n * 3 + (ch - 1)];
  return other[n * 62 + (ch - 4)];
}
__device__ __forceinline__ float atan_poly(float t) {
  float t2 = t * t;
  float p = -0.0117212f;
  p = p * t2 + 0.05265332f;
  p = p * t2 - 0.11643287f;
  p = p * t2 + 0.19354346f;
  p = p * t2 - 0.33262347f;
  p = p * t2 + 0.99997726f;
  return t * p;
}
__device__ __forceinline__ void axis_w(float g, int& i0c, int& i1c, float& w0, float& w1) {
  float c = 2.0f * g + 1.5f;
  float fl = floorf(c);
  float f = c - fl;
  int i0 = (int)fl;
  w0 = (i0 >= 0 && i0 <= 3) ? (1.0f - f) : 0.0f;
  w1 = (i0 >= -1 && i0 <= 2) ? f : 0.0f;
  i0c = min(max(i0, 0), 3);
  i1c = min(max(i0 + 1, 0), 3);
}
__device__ __forceinline__ float dot2f(f16x2 a, f16x2 b, float c) {
#if defined(__has_builtin) && __has_builtin(__builtin_amdgcn_fdot2)
  return __builtin_amdgcn_fdot2(a, b, c, false);
#else
  return c + (float)a[0] * (float)b[0] + (float)a[1] * (float)b[1];
#endif
}

// ============ prep: hT0 + packed KT (5 layers), all sc01 stores ============
// KT layout: elem ((g8*64 + o)*8 + e) = K_row_o[g8*8 + e]; lane o reads 16B -> 1KB/wave.
__device__ void prep_body(const float* __restrict__ v, const float* __restrict__ other,
                          const float* __restrict__ kf, const float* __restrict__ Wf,
                          const float* __restrict__ k1, const float* __restrict__ W1,
                          const float* __restrict__ k2, const float* __restrict__ W2,
                          const float* __restrict__ k3, const float* __restrict__ W3,
                          const float* __restrict__ k4, const float* __restrict__ W4,
                          char* __restrict__ ws) {
  for (int idx = blockIdx.x * 256 + threadIdx.x; idx < PREP_TOTAL; idx += NBLK * 256) {
    int e = idx;
    if (e < 40960) {                         // hT0: feats0^T, rows 66..79 zero
      int i = e >> 9, n = e & 511;
      float val = (i < 66) ? feats0_val(i, n, v, other) : 0.0f;
      st_sys_u16((f16*)(ws + OFF_HT0) + e, f16bits(val));
      continue;
    }
    e -= 40960;
    if (e < 278528) {                        // KT0: conv 4224 | dense 66 | pad->4352
      int o = (e >> 3) & 63;
      int k = ((e >> 9) << 3) + (e & 7);
      float val = 0.0f;
      if (k < 4224) { if (o < 32) val = kf[o * 4224 + k]; }
      else if (k < 4290) { if (o >= 32) val = Wf[(o - 32) * 66 + (k - 4224)]; }
      st_sys_u16((f16*)(ws + OFF_KT0) + e, f16bits(val));
      continue;
    }
    e -= 278528;
    if (e < 798720) {                        // KT1..KT3: conv 4096 | dense 64
      int which = e / 266240, ee = e % 266240;
      const float* kk = which == 0 ? k1 : (which == 1 ? k2 : k3);
      const float* WW = which == 0 ? W1 : (which == 1 ? W2 : W3);
      int o = (ee >> 3) & 63;
      int k = ((ee >> 9) << 3) + (ee & 7);
      float val = (k < 4096) ? kk[o * 4096 + k] : WW[o * 64 + (k - 4096)];
      st_sys_u16((f16*)(ws + OFF_KT1) + (size_t)which * 266240 + ee, f16bits(val));
      continue;
    }
    e -= 798720;
    {                                        // KT4: rows o<6 real, else zero
      int o = (e >> 3) & 63;
      int k = ((e >> 9) << 3) + (e & 7);
      float val = 0.0f;
      if (o < 6) val = (k < 4096) ? k4[o * 4096 + k] : W4[o * 64 + (k - 4096)];
      st_sys_u16((f16*)(ws + OFF_KT4) + e, f16bits(val));
    }
  }
}

// ============ fused layer: block b owns m=b; t stays in LDS ============
template<int LAYER>
__device__ void layer_body(const float* __restrict__ p, const float* __restrict__ mask,
                           const float* __restrict__ v, const float* __restrict__ other,
                           const float* __restrict__ bias, const f16* __restrict__ KT,
                           const f16* __restrict__ hT_in, f16* __restrict__ hT_out,
                           f16* __restrict__ hG, float* __restrict__ outG,
                           float* __restrict__ dout,
                           f16* __restrict__ Wl, f16* __restrict__ tt, float* __restrict__ red) {
  constexpr int CI     = (LAYER == 0) ? 66 : 64;
  constexpr int ITILES = (LAYER == 0) ? 5 : 4;
  constexpr int KD     = (LAYER == 0) ? 4352 : 4160;
  constexpr bool RES   = (LAYER >= 1 && LAYER <= 3);
  constexpr bool FINAL = (LAYER == 4);
  const int tid = threadIdx.x;
  const int m = blockIdx.x;
  const int wave = tid >> 6, lane = tid & 63;
  const int row = lane & 15, kgrp = lane >> 4;
  const int grow = wave * 16 + row;

  // ---------- stage 1: W-scatter (two 256-n halves) + MFMA -> t in LDS ----------
  const float pmx = p[m * 3 + 0], pmy = p[m * 3 + 1], pmz = p[m * 3 + 2];
  f32x4 acc[ITILES];
  #pragma unroll
  for (int it = 0; it < ITILES; ++it) acc[it] = f32x4{0.f, 0.f, 0.f, 0.f};

  #pragma unroll
  for (int half = 0; half < 2; ++half) {
    __syncthreads();
    int4* w4 = (int4*)Wl;
    int4 z4 = make_int4(0, 0, 0, 0);
    #pragma unroll
    for (int i = 0; i < 8; ++i) w4[tid + i * 256] = z4;     // zero 32KB
    __syncthreads();
    {
      const int n = half * 256 + tid;
      float x = (p[n * 3 + 0] - pmx) * INV_R;
      float y = (p[n * 3 + 1] - pmy) * INV_R;
      float z = (p[n * 3 + 2] - pmz) * INV_R;
      float r2 = x * x + y * y + z * z;
      float q = 1.0f - r2;
      float att = (q > 0.0f) ? q * q * q * mask[n] : 0.0f;
      bool c1 = (x == 0.0f) && (y == 0.0f);
      bool c2 = (fabsf(y) <= fabsf(x)) && !c1;
      float r = sqrtf(x * x + y * y + 1e-9f);
      float num = c2 ? y : x;
      float den = c2 ? x : y;
      float a = atan_poly(num / den);
      float s2 = copysignf(r, x), s3 = copysignf(r, y);
      const float C4PI = 1.2732395447351628f;
      float xs = c1 ? 0.0f : (c2 ? s2 : C4PI * s3 * a);
      float ys = c1 ? 0.0f : (c2 ? C4PI * s2 * a : s3);
      float zs = z;
      int iz0, iz1, iy0, iy1, ix0, ix1;
      float wz0, wz1, wy0, wy1, wx0, wx1;
      axis_w(zs, iz0, iz1, wz0, wz1);
      axis_w(ys, iy0, iy1, wy0, wy1);
      axis_w(xs, ix0, ix1, wx0, wx1);
      wz0 *= att; wz1 *= att;
      int gz[2] = {iz0 * 16, iz1 * 16};
      int gy[2] = {iy0 * 4, iy1 * 4};
      int gx[2] = {ix0, ix1};
      float wzv[2] = {wz0, wz1}, wyv[2] = {wy0, wy1}, wxv[2] = {wx0, wx1};
      #pragma unroll
      for (int za = 0; za < 2; ++za)
        #pragma unroll
        for (int ya = 0; ya < 2; ++ya)
          #pragma unroll
          for (int xa = 0; xa < 2; ++xa) {
            float w = wzv[za] * wyv[ya] * wxv[xa];
            if (w != 0.0f) {
              int g = gz[za] + gy[ya] + gx[xa];
              Wl[g * 256 + (tid ^ ((g & 7) << 3))] = (f16)w;
            }
          }
    }
    __syncthreads();
    #pragma unroll
    for (int k0 = 0; k0 < 8; ++k0) {
      const int n0l = k0 * 32 + kgrp * 8;
      f16x8 afrag = *(f16x8*)&Wl[grow * 256 + (n0l ^ ((grow & 7) << 3))];
      #pragma unroll
      for (int it = 0; it < ITILES; ++it) {
        f16x8 bfrag = *(const f16x8*)&hT_in[(it * 16 + row) * 512 + half * 256 + n0l];
        acc[it] = __builtin_amdgcn_mfma_f32_16x16x32_f16(afrag, bfrag, acc[it], 0, 0, 0);
      }
    }
  }
  // write t = [i*64+g] + dense tail
  const int g4 = wave * 16 + kgrp * 4;
  #pragma unroll
  for (int it = 0; it < ITILES; ++it) {
    const int icol = it * 16 + row;
    if (icol < CI) {
      union { f16 h[4]; short4 s; } cv;
      #pragma unroll
      for (int r = 0; r < 4; ++r) cv.h[r] = (f16)acc[it][r];
      *(short4*)&tt[icol * 64 + g4] = cv.s;
    }
  }
  if (LAYER == 0) {
    if (tid < 128)
      tt[4224 + tid] = (f16)((tid < 66) ? feats0_val(tid, m, v, other) : 0.0f);
  } else {
    if (tid < 64) tt[4096 + tid] = hG[m * 64 + tid];        // block-private row
  }
  __syncthreads();

  // ---------- stage 2: out[m,o] = t . K[o,:] via dot2, wave = k-split ----------
  constexpr int GPS = KD / 32;
  {
    const int o = tid & 63, wv = tid >> 6;
    float a0 = 0.f;
    const f16* kp = KT + ((size_t)(wv * GPS) * 64 + o) * 8;
    const f16* tp = tt + (size_t)(wv * GPS) * 8;
    for (int g = 0; g < GPS; ++g) {
      union { f16x8 v8; f16x2 p2[4]; } uk, u0;
      uk.v8 = *(const f16x8*)kp;
      u0.v8 = *(const f16x8*)tp;               // LDS broadcast (uniform per wave)
      kp += 512; tp += 8;
      #pragma unroll
      for (int j = 0; j < 4; ++j) a0 = dot2f(uk.p2[j], u0.p2[j], a0);
    }
    red[wv * 64 + o] = a0;
  }
  __syncthreads();
  if (tid < 64) {
    const int oo = tid;
    float s = red[oo] + red[64 + oo] + red[128 + oo] + red[192 + oo];
    if (FINAL) {
      if (oo < 6) dout[m * 6 + oo] = s + bias[oo];
    } else {
      float bb = (LAYER == 0) ? ((oo < 32) ? 0.0f : bias[oo - 32]) : bias[oo];
      float val = s + bb;
      if (RES) val += outG[m * 64 + oo];       // block-private row
      outG[m * 64 + oo] = val;
      float h = fmaxf(val, 0.0f);
      hG[m * 64 + oo] = (f16)h;                // block-private
      st_sys_u16(&hT_out[oo * 512 + m], f16bits(h));   // cross-block (sc01)
    }
  }
}

// ================= cooperative mega-kernel =================
__global__ __launch_bounds__(256) void mega_kernel(
    const float* p, const float* v, const float* other, const float* mask,
    const float* kf, const float* Wf, const float* bf,
    const float* k1, const float* W1, const float* b1,
    const float* k2, const float* W2, const float* b2,
    const float* k3, const float* W3, const float* b3,
    const float* k4, const float* W4, const float* b4,
    float* dout, char* ws) {
  __shared__ int4 blob[2656];                // 42496 B: W 32KB | t 8.5KB | red 1KB
  f16* Wl = (f16*)blob;
  f16* tt = Wl + 16384;
  float* red = (float*)(tt + 4352);
  unsigned* bar = (unsigned*)(ws + OFF_BAR);

  f16* hT0 = (f16*)(ws + OFF_HT0);
  f16* hT1 = (f16*)(ws + OFF_HT1);
  f16* hT2 = (f16*)(ws + OFF_HT2);
  f16* hT3 = (f16*)(ws + OFF_HT3);
  f16* hT4 = (f16*)(ws + OFF_HT4);
  f16* hG  = (f16*)(ws + OFF_HG);
  float* outG = (float*)(ws + OFF_OG);

  prep_body(v, other, kf, Wf, k1, W1, k2, W2, k3, W3, k4, W4, ws);
  gridbar(bar, 0);
  layer_body<0>(p, mask, v, other, bf, (const f16*)(ws + OFF_KT0), hT0, hT1, hG, outG, nullptr, Wl, tt, red);
  gridbar(bar, 1);
  layer_body<1>(p, mask, v, other, b1, (const f16*)(ws + OFF_KT1), hT1, hT2, hG, outG, nullptr, Wl, tt, red);
  gridbar(bar, 2);
  layer_body<2>(p, mask, v, other, b2, (const f16*)(ws + OFF_KT2), hT2, hT3, hG, outG, nullptr, Wl, tt, red);
  gridbar(bar, 3);
  layer_body<3>(p, mask, v, other, b3, (const f16*)(ws + OFF_KT3), hT3, hT4, hG, outG, nullptr, Wl, tt, red);
  gridbar(bar, 4);
  layer_body<4>(p, mask, v, other, b4, (const f16*)(ws + OFF_KT4), hT4, nullptr, hG, outG, dout, Wl, tt, red);
}

// ================= fallback: 6 plain launches of the same bodies =================
__global__ __launch_bounds__(256) void prep_g(
    const float* v, const float* other, const float* kf, const float* Wf,
    const float* k1, const float* W1, const float* k2, const float* W2,
    const float* k3, const float* W3, const float* k4, const float* W4, char* ws) {
  prep_body(v, other, kf, Wf, k1, W1, k2, W2, k3, W3, k4, W4, ws);
}

template<int LAYER>
__global__ __launch_bounds__(256) void layer_g(
    const float* p, const float* mask, const float* v, const float* other,
    const float* bias, const f16* KT, const f16* hT_in, f16* hT_out,
    f16* hG, float* outG, float* dout) {
  __shared__ int4 blob[2656];
  f16* Wl = (f16*)blob;
  f16* tt = Wl + 16384;
  float* red = (float*)(tt + 4352);
  layer_body<LAYER>(p, mask, v, other, bias, KT, hT_in, hT_out, hG, outG, dout, Wl, tt, red);
}

extern "C" void kernel_launch(void* const* d_in, const int* in_sizes, int n_in,
                              void* d_out, int out_size, void* d_ws, size_t ws_size,
                              hipStream_t stream) {
  const float* p     = (const float*)d_in[0];
  const float* v     = (const float*)d_in[1];
  const float* other = (const float*)d_in[2];
  const float* mask  = (const float*)d_in[3];
  const float* kf    = (const float*)d_in[4];
  const float* Wf    = (const float*)d_in[5];
  const float* bf    = (const float*)d_in[6];
  const float* k1    = (const float*)d_in[7];
  const float* W1    = (const float*)d_in[8];
  const float* b1    = (const float*)d_in[9];
  const float* k2    = (const float*)d_in[10];
  const float* W2    = (const float*)d_in[11];
  const float* b2    = (const float*)d_in[12];
  const float* k3    = (const float*)d_in[13];
  const float* W3    = (const float*)d_in[14];
  const float* b3    = (const float*)d_in[15];
  const float* k4    = (const float*)d_in[16];
  const float* W4    = (const float*)d_in[17];
  const float* b4    = (const float*)d_in[18];
  float* dout = (float*)d_out;
  char* ws = (char*)d_ws;
  (void)in_sizes; (void)n_in; (void)out_size; (void)ws_size;

  const f16* KT0 = (const f16*)(ws + OFF_KT0);
  const f16* KT1 = (const f16*)(ws + OFF_KT1);
  const f16* KT2 = (const f16*)(ws + OFF_KT2);
  const f16* KT3 = (const f16*)(ws + OFF_KT3);
  const f16* KT4c = (const f16*)(ws + OFF_KT4);
  f16* hT0 = (f16*)(ws + OFF_HT0);
  f16* hT1 = (f16*)(ws + OFF_HT1);
  f16* hT2 = (f16*)(ws + OFF_HT2);
  f16* hT3 = (f16*)(ws + OFF_HT3);
  f16* hT4 = (f16*)(ws + OFF_HT4);
  f16* hG  = (f16*)(ws + OFF_HG);
  float* outG = (float*)(ws + OFF_OG);

  // ---- cooperative fused path (needs 2 blocks/CU for 512-block co-residency) ----
  int maxb = 0;
  hipError_t e1 = hipOccupancyMaxActiveBlocksPerMultiprocessor(
      &maxb, (const void*)mega_kernel, 256, 0);
  if (e1 == hipSuccess && maxb >= 2) {
    hipMemsetAsync(ws + OFF_BAR, 0, 2304, stream);
    void* args[] = {
      (void*)&p, (void*)&v, (void*)&other, (void*)&mask,
      (void*)&kf, (void*)&Wf, (void*)&bf,
      (void*)&k1, (void*)&W1, (void*)&b1,
      (void*)&k2, (void*)&W2, (void*)&b2,
      (void*)&k3, (void*)&W3, (void*)&b3,
      (void*)&k4, (void*)&W4, (void*)&b4,
      (void*)&dout, (void*)&ws
    };
    hipError_t e2 = hipLaunchCooperativeKernel((const void*)mega_kernel, dim3(NBLK),
                                               dim3(256), args, 0, stream);
    if (e2 == hipSuccess) return;
  }

  // ---- fallback: same bodies, dispatch-boundary coherence ----
  prep_g<<<NBLK, 256, 0, stream>>>(v, other, kf, Wf, k1, W1, k2, W2, k3, W3, k4, W4, ws);
  layer_g<0><<<NBLK, 256, 0, stream>>>(p, mask, v, other, bf, KT0, hT0, hT1, hG, outG, nullptr);
  layer_g<1><<<NBLK, 256, 0, stream>>>(p, mask, v, other, b1, KT1, hT1, hT2, hG, outG, nullptr);
  layer_g<2><<<NBLK, 256, 0, stream>>>(p, mask, v, other, b2, KT2, hT2, hT3, hG, outG, nullptr);
  layer_g<3><<<NBLK, 256, 0, stream>>>(p, mask, v, other, b3, KT3, hT3, hT4, hG, outG, nullptr);
  layer_g<4><<<NBLK, 256, 0, stream>>>(p, mask, v, other, b4, KT4c, hT4, nullptr, hG, outG, dout);
}